// Round 2
// baseline (24267.162 us; speedup 1.0000x reference)
//
#include <hip/hip_runtime.h>
#include <hip/hip_bf16.h>

#define D_MODEL 768
#define NH 24
#define HP 64
#define NSTATE 64
#define DIN 1536
#define CONV_DIM 1664
#define DPROJ 3224
#define TLEN 4161
#define IMG 4096
#define NCHUNK 33
#define CHUNK 128
#define TPAD (NCHUNK*CHUNK)

__device__ __forceinline__ float softplusf(float x) { return x > 20.f ? x : log1pf(expf(x)); }
__device__ __forceinline__ float siluf(float x) { return x / (1.f + expf(-x)); }

// ---------------- embed / build x ----------------
__global__ void e8_kernel(const float* __restrict__ im8, const float* __restrict__ w,
                          const float* __restrict__ b, float* __restrict__ e8) {
  int gid = blockIdx.x * blockDim.x + threadIdx.x;
  if (gid >= 64 * D_MODEL) return;
  int j = gid / D_MODEL, d = gid % D_MODEL;
  float acc = b[d];
  for (int c = 0; c < 3; c++) acc += im8[j * 3 + c] * w[d * 3 + c];
  e8[gid] = acc;
}

__global__ void build_x_kernel(const float* __restrict__ e8, const float* __restrict__ s0,
                               const float* __restrict__ suffix, float* __restrict__ out) {
  for (int gid = blockIdx.x * blockDim.x + threadIdx.x; gid < TLEN * D_MODEL;
       gid += gridDim.x * blockDim.x) {
    int t = gid / D_MODEL, d = gid % D_MODEL;
    float v;
    if (t == 0) v = s0[d];
    else if (t < 65) v = e8[(t - 1) * D_MODEL + d];
    else {
      int i = t - 65;
      int r = i >> 6, c = i & 63;
      v = e8[((r >> 3) * 8 + (c >> 3)) * D_MODEL + d] + suffix[(size_t)i * D_MODEL + d];
    }
    out[gid] = v;
  }
}

// ---------------- layer norm (cols = 768) ----------------
__global__ __launch_bounds__(256) void ln_kernel(const float* __restrict__ in,
                                                 const float* __restrict__ w, const float* __restrict__ b,
                                                 float* __restrict__ out, int rows) {
  int r = blockIdx.x;
  if (r >= rows) return;
  const float* row = in + (size_t)r * D_MODEL;
  __shared__ float red[256];
  int tid = threadIdx.x;
  float v0 = row[tid], v1 = row[tid + 256], v2 = row[tid + 512];
  red[tid] = v0 + v1 + v2;
  __syncthreads();
  for (int o = 128; o; o >>= 1) { if (tid < o) red[tid] += red[tid + o]; __syncthreads(); }
  float mu = red[0] / (float)D_MODEL;
  __syncthreads();
  float d0 = v0 - mu, d1 = v1 - mu, d2 = v2 - mu;
  red[tid] = d0 * d0 + d1 * d1 + d2 * d2;
  __syncthreads();
  for (int o = 128; o; o >>= 1) { if (tid < o) red[tid] += red[tid + o]; __syncthreads(); }
  float inv = rsqrtf(red[0] / (float)D_MODEL + 1e-5f);
  float* orow = out + (size_t)r * D_MODEL;
  orow[tid]       = d0 * inv * w[tid]       + b[tid];
  orow[tid + 256] = d1 * inv * w[tid + 256] + b[tid + 256];
  orow[tid + 512] = d2 * inv * w[tid + 512] + b[tid + 512];
}

// ---------------- GEMM: C(M,N) = A(M,K) * B(N,K)^T ----------------
#define BM 64
#define BN 64
#define BK 16
__global__ __launch_bounds__(256) void gemm_f32(const float* __restrict__ A,
                                                const float* __restrict__ B,
                                                float* __restrict__ C, int M, int N, int K) {
  __shared__ float As[BK][BM + 4];
  __shared__ float Bs[BK][BN + 4];
  int bm = blockIdx.x * BM;
  int bn = blockIdx.y * BN;
  int tid = threadIdx.x;
  int tx = tid & 15, ty = tid >> 4;
  float acc[4][4] = {};
  for (int k0 = 0; k0 < K; k0 += BK) {
    for (int e = 0; e < 4; e++) {
      int idx = tid + e * 256;
      int m = idx >> 4;
      int k = idx & 15;
      int gm = bm + m, gn = bn + m, gk = k0 + k;
      As[k][m] = (gm < M) ? A[(size_t)gm * K + gk] : 0.f;
      Bs[k][m] = (gn < N) ? B[(size_t)gn * K + gk] : 0.f;
    }
    __syncthreads();
    for (int k = 0; k < BK; k++) {
      float a[4], bb[4];
      #pragma unroll
      for (int i = 0; i < 4; i++) a[i] = As[k][ty * 4 + i];
      #pragma unroll
      for (int j = 0; j < 4; j++) bb[j] = Bs[k][tx * 4 + j];
      #pragma unroll
      for (int i = 0; i < 4; i++)
        #pragma unroll
        for (int j = 0; j < 4; j++) acc[i][j] += a[i] * bb[j];
    }
    __syncthreads();
  }
  for (int i = 0; i < 4; i++) {
    int gm = bm + ty * 4 + i;
    if (gm >= M) continue;
    for (int j = 0; j < 4; j++) {
      int gn = bn + tx * 4 + j;
      if (gn < N) C[(size_t)gm * N + gn] = acc[i][j];
    }
  }
}

// ---------------- conv1d (depthwise causal k=4) + silu ----------------
__global__ void conv1d_kernel(const float* __restrict__ zx, const float* __restrict__ cw,
                              const float* __restrict__ cb, float* __restrict__ xBC) {
  for (int gid = blockIdx.x * blockDim.x + threadIdx.x; gid < TLEN * CONV_DIM;
       gid += gridDim.x * blockDim.x) {
    int t = gid / CONV_DIM, ch = gid % CONV_DIM;
    float acc = cb[ch];
    #pragma unroll
    for (int k = 0; k < 4; k++) {
      int tt = t - 3 + k;
      if (tt >= 0) acc += zx[(size_t)tt * DPROJ + DIN + ch] * cw[ch * 4 + k];
    }
    xBC[gid] = siluf(acc);
  }
}

__global__ void dt_kernel(const float* __restrict__ zx, const float* __restrict__ dt_bias,
                          float* __restrict__ dt) {
  for (int gid = blockIdx.x * blockDim.x + threadIdx.x; gid < TLEN * NH;
       gid += gridDim.x * blockDim.x) {
    int t = gid / NH, h = gid % NH;
    float v = zx[(size_t)t * DPROJ + DPROJ - NH + h] + dt_bias[h];
    dt[gid] = softplusf(v);
  }
}

// ---------------- A cumsum per chunk/head ----------------
__global__ void acs_kernel(const float* __restrict__ dt, const float* __restrict__ A_log,
                           float* __restrict__ Acs, float* __restrict__ csum) {
  int gid = blockIdx.x * blockDim.x + threadIdx.x;
  if (gid >= NCHUNK * NH) return;
  int c = gid / NH, h = gid % NH;
  float A = -expf(A_log[h]);
  float acc = 0.f;
  for (int l = 0; l < CHUNK; l++) {
    int t = c * CHUNK + l;
    float a = (t < TLEN) ? dt[(size_t)t * NH + h] * A : 0.f;
    acc += a;
    Acs[(size_t)(c * CHUNK + l) * NH + h] = acc;
  }
  csum[c * NH + h] = acc;
}

// ---------------- per-chunk state: cstate[c][h][p][n] ----------------
__global__ __launch_bounds__(256) void chunk_state_kernel(const float* __restrict__ xBC,
                                                          const float* __restrict__ dt,
                                                          const float* __restrict__ Acs,
                                                          const float* __restrict__ csum,
                                                          float* __restrict__ cstate) {
  int c = blockIdx.x, h = blockIdx.y;
  __shared__ float Bs[CHUNK][NSTATE];
  __shared__ float Xs[CHUNK][HP];
  int tid = threadIdx.x;
  float cs = csum[c * NH + h];
  for (int idx = tid; idx < CHUNK * 64; idx += 256) {
    int l = idx >> 6, n = idx & 63;
    int t = c * CHUNK + l;
    if (t < TLEN) {
      float a = Acs[(size_t)t * NH + h];
      Bs[l][n] = xBC[(size_t)t * CONV_DIM + DIN + n];
      Xs[l][n] = xBC[(size_t)t * CONV_DIM + h * HP + n] * dt[(size_t)t * NH + h] * expf(cs - a);
    } else { Bs[l][n] = 0.f; Xs[l][n] = 0.f; }
  }
  __syncthreads();
  int pt = (tid >> 4) * 4, nt = (tid & 15) * 4;
  float acc[4][4] = {};
  for (int l = 0; l < CHUNK; l++) {
    float xv[4], bv[4];
    #pragma unroll
    for (int i = 0; i < 4; i++) xv[i] = Xs[l][pt + i];
    #pragma unroll
    for (int j = 0; j < 4; j++) bv[j] = Bs[l][nt + j];
    #pragma unroll
    for (int i = 0; i < 4; i++)
      #pragma unroll
      for (int j = 0; j < 4; j++) acc[i][j] += xv[i] * bv[j];
  }
  size_t base = (((size_t)c * NH) + h) * 64 * 64;
  for (int i = 0; i < 4; i++)
    for (int j = 0; j < 4; j++)
      cstate[base + (size_t)(pt + i) * 64 + nt + j] = acc[i][j];
}

// ---------------- sequential inter-chunk scan ----------------
__global__ __launch_bounds__(256) void state_scan_kernel(const float* __restrict__ cstate,
                                                         const float* __restrict__ csum,
                                                         float* __restrict__ sstate) {
  int h = blockIdx.x;
  int tid = threadIdx.x;
  float S[16];
  #pragma unroll
  for (int j = 0; j < 16; j++) S[j] = 0.f;
  for (int z = 0; z < NCHUNK; z++) {
    size_t base = (((size_t)z * NH) + h) * 4096;
    float dec = expf(csum[z * NH + h]);
    #pragma unroll
    for (int j = 0; j < 16; j++) {
      int idx = j * 256 + tid;
      sstate[base + idx] = S[j];
      S[j] = S[j] * dec + cstate[base + idx];
    }
  }
}

// ---------------- SSD output Y = Yd + Yo + Dp*xh ----------------
__global__ __launch_bounds__(256, 1) void ssd_y_kernel(const float* __restrict__ xBC,
                                                       const float* __restrict__ dt,
                                                       const float* __restrict__ Acs,
                                                       const float* __restrict__ sstate,
                                                       const float* __restrict__ Dp,
                                                       float* __restrict__ y) {
  int c = blockIdx.x, h = blockIdx.y;
  __shared__ float Cs[CHUNK][NSTATE];
  __shared__ float Bx[CHUNK][NSTATE];   // Bm, then Xs, then Ssh(64x64)
  __shared__ float Gm[CHUNK][CHUNK];
  __shared__ float Ash[CHUNK];
  int tid = threadIdx.x;
  for (int idx = tid; idx < CHUNK * 64; idx += 256) {
    int l = idx >> 6, n = idx & 63;
    int t = c * CHUNK + l;
    bool v = t < TLEN;
    Cs[l][n] = v ? xBC[(size_t)t * CONV_DIM + DIN + NSTATE + n] : 0.f;
    Bx[l][n] = v ? xBC[(size_t)t * CONV_DIM + DIN + n] : 0.f;
  }
  if (tid < CHUNK) Ash[tid] = Acs[(size_t)(c * CHUNK + tid) * NH + h];
  __syncthreads();
  // G = C B^T with mask*decay
  {
    int lt = (tid >> 4) * 8, st = (tid & 15) * 8;
    float acc[8][8] = {};
    for (int n = 0; n < 64; n++) {
      float cv[8], bv[8];
      #pragma unroll
      for (int i = 0; i < 8; i++) cv[i] = Cs[lt + i][n];
      #pragma unroll
      for (int j = 0; j < 8; j++) bv[j] = Bx[st + j][n];
      #pragma unroll
      for (int i = 0; i < 8; i++)
        #pragma unroll
        for (int j = 0; j < 8; j++) acc[i][j] += cv[i] * bv[j];
    }
    for (int i = 0; i < 8; i++)
      for (int j = 0; j < 8; j++) {
        int l = lt + i, s = st + j;
        Gm[l][s] = (s <= l) ? acc[i][j] * expf(Ash[l] - Ash[s]) : 0.f;
      }
  }
  __syncthreads();
  // Xs into Bx
  for (int idx = tid; idx < CHUNK * 64; idx += 256) {
    int l = idx >> 6, p = idx & 63;
    int t = c * CHUNK + l;
    Bx[l][p] = (t < TLEN) ? xBC[(size_t)t * CONV_DIM + h * HP + p] * dt[(size_t)t * NH + h] : 0.f;
  }
  __syncthreads();
  int lt = (tid >> 4) * 8, pt = (tid & 15) * 4;
  float yd[8][4] = {};
  for (int s = 0; s < CHUNK; s++) {
    float m8[8], x4[4];
    #pragma unroll
    for (int i = 0; i < 8; i++) m8[i] = Gm[lt + i][s];
    #pragma unroll
    for (int j = 0; j < 4; j++) x4[j] = Bx[s][pt + j];
    #pragma unroll
    for (int i = 0; i < 8; i++)
      #pragma unroll
      for (int j = 0; j < 4; j++) yd[i][j] += m8[i] * x4[j];
  }
  __syncthreads();
  // Ssh into Bx
  for (int idx = tid; idx < 64 * 64; idx += 256) {
    int p = idx >> 6, n = idx & 63;
    Bx[p][n] = sstate[(((size_t)c * NH) + h) * 4096 + idx];
  }
  __syncthreads();
  float yo[8][4] = {};
  for (int n = 0; n < 64; n++) {
    float c8[8], s4[4];
    #pragma unroll
    for (int i = 0; i < 8; i++) c8[i] = Cs[lt + i][n];
    #pragma unroll
    for (int j = 0; j < 4; j++) s4[j] = Bx[pt + j][n];
    #pragma unroll
    for (int i = 0; i < 8; i++)
      #pragma unroll
      for (int j = 0; j < 4; j++) yo[i][j] += c8[i] * s4[j];
  }
  float dph = Dp[h];
  for (int i = 0; i < 8; i++) {
    int l = lt + i, t = c * CHUNK + l;
    if (t >= TLEN) continue;
    float ea = expf(Ash[l]);
    for (int j = 0; j < 4; j++) {
      int p = pt + j;
      float xh = xBC[(size_t)t * CONV_DIM + h * HP + p];
      y[(size_t)t * DIN + h * HP + p] = yd[i][j] + ea * yo[i][j] + dph * xh;
    }
  }
}

// ---------------- gate (silu(z)) + RMS norm over 1536 ----------------
__global__ __launch_bounds__(256) void gate_rms_kernel(float* __restrict__ y,
                                                       const float* __restrict__ zx,
                                                       const float* __restrict__ rms_w) {
  int t = blockIdx.x;
  if (t >= TLEN) return;
  __shared__ float red[256];
  int tid = threadIdx.x;
  float v[6];
  float ss = 0.f;
  #pragma unroll
  for (int e = 0; e < 6; e++) {
    int d = e * 256 + tid;
    float z = zx[(size_t)t * DPROJ + d];
    float val = y[(size_t)t * DIN + d] * siluf(z);
    v[e] = val;
    ss += val * val;
  }
  red[tid] = ss;
  __syncthreads();
  for (int o = 128; o; o >>= 1) { if (tid < o) red[tid] += red[tid + o]; __syncthreads(); }
  float scale = rsqrtf(red[0] / (float)DIN + 1e-5f);
  #pragma unroll
  for (int e = 0; e < 6; e++) {
    int d = e * 256 + tid;
    y[(size_t)t * DIN + d] = v[e] * scale * rms_w[d];
  }
}

// ---------------- conv2d 5x5 SAME, 768->768 ----------------
#define CPT 4
__global__ __launch_bounds__(256) void conv2d_kernel(const float* __restrict__ in,
                                                     const float* __restrict__ W,
                                                     const float* __restrict__ bias,
                                                     float* __restrict__ out) {
  __shared__ float P[12 * 12 * CPT];
  __shared__ float Ws[25][CPT][64];
  int tr = (blockIdx.x >> 3) * 8, tc = (blockIdx.x & 7) * 8;
  int oc0 = blockIdx.y * 64;
  int tid = threadIdx.x;
  int pix_b = (tid >> 4) * 4;
  int oc_b = (tid & 15) * 4;
  float acc[4][4] = {};
  for (int ic0 = 0; ic0 < D_MODEL; ic0 += CPT) {
    for (int idx = tid; idx < 144 * CPT; idx += 256) {
      int pp = idx / CPT, ic = idx % CPT;
      int pr = pp / 12, pc = pp % 12;
      int gr = tr + pr - 2, gc = tc + pc - 2;
      P[idx] = (gr >= 0 && gr < 64 && gc >= 0 && gc < 64)
                   ? in[((size_t)(gr * 64 + gc)) * D_MODEL + ic0 + ic] : 0.f;
    }
    for (int idx = tid; idx < 25 * CPT * 64; idx += 256) {
      int tap = idx / (CPT * 64);
      int rem = idx % (CPT * 64);
      int ic = rem / 64, oc = rem % 64;
      Ws[tap][ic][oc] = W[((size_t)tap * D_MODEL + ic0 + ic) * D_MODEL + oc0 + oc];
    }
    __syncthreads();
    for (int tap = 0; tap < 25; tap++) {
      int dr = tap / 5, dc = tap % 5;
      #pragma unroll
      for (int ic = 0; ic < CPT; ic++) {
        float b4[4];
        #pragma unroll
        for (int j = 0; j < 4; j++) b4[j] = Ws[tap][ic][oc_b + j];
        #pragma unroll
        for (int i = 0; i < 4; i++) {
          int p = pix_b + i;
          int pr = (p >> 3) + dr, pc = (p & 7) + dc;
          float a = P[(pr * 12 + pc) * CPT + ic];
          #pragma unroll
          for (int j = 0; j < 4; j++) acc[i][j] += a * b4[j];
        }
      }
    }
    __syncthreads();
  }
  for (int i = 0; i < 4; i++) {
    int p = pix_b + i;
    int gp = (tr + (p >> 3)) * 64 + (tc + (p & 7));
    for (int j = 0; j < 4; j++)
      out[(size_t)gp * D_MODEL + oc0 + oc_b + j] = acc[i][j] + bias[oc0 + oc_b + j];
  }
}

// ---------------- residual add + image flip ----------------
__global__ void resadd_flip_kernel(const float* __restrict__ x, const float* __restrict__ hbuf,
                                   float* __restrict__ xnew) {
  for (int gid = blockIdx.x * blockDim.x + threadIdx.x; gid < TLEN * D_MODEL;
       gid += gridDim.x * blockDim.x) {
    int t = gid / D_MODEL, d = gid % D_MODEL;
    int st = (t < 65) ? t : 65 + (IMG - 1 - (t - 65));
    size_t sidx = (size_t)st * D_MODEL + d;
    xnew[gid] = x[sidx] + hbuf[sidx];
  }
}

// ---------------- head: y_hat + loss ----------------
__global__ void zero_loss_kernel(float* loss) { *loss = 0.f; }

__global__ void head_kernel(const float* __restrict__ ximg, const float* __restrict__ w,
                            const float* __restrict__ b, const float* __restrict__ im64,
                            float* __restrict__ out, float* __restrict__ loss_acc) {
  int p = blockIdx.x;
  int lane = threadIdx.x;
  const float* row = ximg + (size_t)p * D_MODEL;
  float a0 = 0.f, a1 = 0.f, a2 = 0.f;
  for (int d = lane; d < D_MODEL; d += 64) {
    float xv = row[d];
    a0 += xv * w[d];
    a1 += xv * w[D_MODEL + d];
    a2 += xv * w[2 * D_MODEL + d];
  }
  for (int off = 32; off; off >>= 1) {
    a0 += __shfl_down(a0, off);
    a1 += __shfl_down(a1, off);
    a2 += __shfl_down(a2, off);
  }
  if (lane == 0) {
    a0 += b[0]; a1 += b[1]; a2 += b[2];
    out[p * 3 + 0] = a0;
    out[p * 3 + 1] = a1;
    out[p * 3 + 2] = a2;
    float e0 = a0 - im64[p * 3 + 0];
    float e1 = a1 - im64[p * 3 + 1];
    float e2 = a2 - im64[p * 3 + 2];
    atomicAdd(loss_acc, e0 * e0 + e1 * e1 + e2 * e2);
  }
}

__global__ void finalize_loss_kernel(const float* __restrict__ loss_acc, float* __restrict__ out) {
  out[IMG * 3] = loss_acc[0] / (float)(IMG * 3);
}

extern "C" void kernel_launch(void* const* d_in, const int* in_sizes, int n_in,
                              void* d_out, int out_size, void* d_ws, size_t ws_size,
                              hipStream_t stream) {
  const float* im8       = (const float*)d_in[0];
  const float* im64      = (const float*)d_in[1];
  const float* from_rgb_w= (const float*)d_in[2];
  const float* from_rgb_b= (const float*)d_in[3];
  const float* to_rgb_w  = (const float*)d_in[4];
  const float* to_rgb_b  = (const float*)d_in[5];
  const float* s0        = (const float*)d_in[6];
  const float* suffix    = (const float*)d_in[7];
  const float* norm0_w   = (const float*)d_in[8];
  const float* norm0_b   = (const float*)d_in[9];
  const float* in_proj_w = (const float*)d_in[10];
  const float* conv1d_w  = (const float*)d_in[11];
  const float* conv1d_b  = (const float*)d_in[12];
  const float* dt_bias   = (const float*)d_in[13];
  const float* A_log     = (const float*)d_in[14];
  const float* Dp        = (const float*)d_in[15];
  const float* rms_w     = (const float*)d_in[16];
  const float* out_proj_w= (const float*)d_in[17];
  const float* ln_w      = (const float*)d_in[18];
  const float* ln_b      = (const float*)d_in[19];
  const float* lnc_w     = (const float*)d_in[20];
  const float* lnc_b     = (const float*)d_in[21];
  const float* conv2d_w  = (const float*)d_in[22];
  const float* conv2d_b  = (const float*)d_in[23];

  float* W = (float*)d_ws;
  size_t off = 0;
  auto alloc = [&](size_t n) { float* p = W + off; off += n; return p; };
  float* xA     = alloc((size_t)TLEN * D_MODEL);
  float* xB     = alloc((size_t)TLEN * D_MODEL);
  float* hbuf   = alloc((size_t)TLEN * D_MODEL);
  float* zx     = alloc((size_t)TLEN * DPROJ);
  float* xBC    = alloc((size_t)TLEN * CONV_DIM);
  float* dtb    = alloc((size_t)TLEN * NH);
  float* Acs    = alloc((size_t)TPAD * NH);
  float* csum   = alloc((size_t)NCHUNK * NH);
  float* ybuf   = alloc((size_t)TLEN * DIN);
  float* cstate = alloc((size_t)NCHUNK * NH * 64 * 64);
  float* sstate = alloc((size_t)NCHUNK * NH * 64 * 64);
  float* imgbuf = alloc((size_t)IMG * D_MODEL);
  float* e8     = alloc((size_t)64 * D_MODEL);
  float* lossp  = alloc(4);
  (void)ws_size; (void)in_sizes; (void)n_in; (void)out_size;

  float* outp = (float*)d_out;

  e8_kernel<<<(64 * D_MODEL + 255) / 256, 256, 0, stream>>>(im8, from_rgb_w, from_rgb_b, e8);
  build_x_kernel<<<2048, 256, 0, stream>>>(e8, s0, suffix, xB);
  ln_kernel<<<TLEN, 256, 0, stream>>>(xB, norm0_w, norm0_b, xA, TLEN);

  float* x = xA;
  float* xn = xB;
  for (int i = 0; i < 8; i++) {
    const float* ipw = in_proj_w + (size_t)i * DPROJ * D_MODEL;
    const float* cw  = conv1d_w + (size_t)i * CONV_DIM * 4;
    const float* cb  = conv1d_b + (size_t)i * CONV_DIM;
    const float* dtbias_i = dt_bias + (size_t)i * NH;
    const float* alog_i   = A_log + (size_t)i * NH;
    const float* dp_i     = Dp + (size_t)i * NH;
    const float* rmsw_i   = rms_w + (size_t)i * DIN;
    const float* opw      = out_proj_w + (size_t)i * D_MODEL * DIN;
    const float* lnw_i    = ln_w + (size_t)i * D_MODEL;
    const float* lnb_i    = ln_b + (size_t)i * D_MODEL;
    const float* lncw_i   = lnc_w + (size_t)i * D_MODEL;
    const float* lncb_i   = lnc_b + (size_t)i * D_MODEL;
    const float* c2w      = conv2d_w + (size_t)i * 25 * D_MODEL * D_MODEL;
    const float* c2b      = conv2d_b + (size_t)i * D_MODEL;

    ln_kernel<<<TLEN, 256, 0, stream>>>(x, lnw_i, lnb_i, hbuf, TLEN);
    {
      dim3 g((TLEN + BM - 1) / BM, (DPROJ + BN - 1) / BN);
      gemm_f32<<<g, 256, 0, stream>>>(hbuf, ipw, zx, TLEN, DPROJ, D_MODEL);
    }
    conv1d_kernel<<<4096, 256, 0, stream>>>(zx, cw, cb, xBC);
    dt_kernel<<<(TLEN * NH + 255) / 256, 256, 0, stream>>>(zx, dtbias_i, dtb);
    acs_kernel<<<(NCHUNK * NH + 255) / 256, 256, 0, stream>>>(dtb, alog_i, Acs, csum);
    chunk_state_kernel<<<dim3(NCHUNK, NH), 256, 0, stream>>>(xBC, dtb, Acs, csum, cstate);
    state_scan_kernel<<<NH, 256, 0, stream>>>(cstate, csum, sstate);
    ssd_y_kernel<<<dim3(NCHUNK, NH), 256, 0, stream>>>(xBC, dtb, Acs, sstate, dp_i, ybuf);
    gate_rms_kernel<<<TLEN, 256, 0, stream>>>(ybuf, zx, rmsw_i);
    {
      dim3 g((TLEN + BM - 1) / BM, (D_MODEL + BN - 1) / BN);
      gemm_f32<<<g, 256, 0, stream>>>(ybuf, opw, hbuf, TLEN, D_MODEL, DIN);
    }
    ln_kernel<<<IMG, 256, 0, stream>>>(hbuf + (size_t)65 * D_MODEL, lncw_i, lncb_i, imgbuf, IMG);
    conv2d_kernel<<<dim3(64, 12), 256, 0, stream>>>(imgbuf, c2w, c2b, hbuf + (size_t)65 * D_MODEL);
    resadd_flip_kernel<<<2048, 256, 0, stream>>>(x, hbuf, xn);
    float* tmp = x; x = xn; xn = tmp;
  }

  zero_loss_kernel<<<1, 1, 0, stream>>>(lossp);
  head_kernel<<<IMG, 64, 0, stream>>>(x + (size_t)65 * D_MODEL, to_rgb_w, to_rgb_b, im64,
                                      outp, lossp);
  finalize_loss_kernel<<<1, 1, 0, stream>>>(lossp, outp);
}